// Round 9
// baseline (144.326 us; speedup 1.0000x reference)
//
#include <hip/hip_runtime.h>
#include <math.h>

#define BB 2
#define NN 2048
#define NP1 2049
#define DM 128
#define NH 8
#define DK 16
#define RWIN 4
#define GRID_W 64
#define WPB 4        /* waves (queries) per block */
#define CAND 160     /* per-query candidate cap; binom mean ~36, sd ~6 */

// ---------------- QKV projection (unchanged from R7) ----------------

#define QKV_ROWS 8

__global__ __launch_bounds__(384) void qkv_kernel(
    const float* __restrict__ z, const float* __restrict__ patch,
    const float* __restrict__ Wq, const float* __restrict__ bq,
    const float* __restrict__ Wk, const float* __restrict__ bk,
    const float* __restrict__ Wv, const float* __restrict__ bv,
    float* __restrict__ q, float* __restrict__ k, float* __restrict__ v) {
    __shared__ float zrow[QKV_ROWS][DM];
    const int tid = threadIdx.x;
    const int mat = tid >> 7;          // 0=q 1=k 2=v, wave-uniform
    const int rem = tid & 127;
    const int cg = rem & 31;           // col-group: cols cg*4..cg*4+3
    const int rs = rem >> 5;           // row-slot: rows rs, rs+4
    const int r0 = blockIdx.x * QKV_ROWS;
    const int NROWS = BB * NP1;

    if (tid < QKV_ROWS * DM / 4) {
        int r = tid >> 5, q4 = tid & 31;
        int row = r0 + r;
        float4 val = make_float4(0.f, 0.f, 0.f, 0.f);
        if (row < NROWS) {
            int b = row / NP1, ti = row % NP1;
            const float* src = (ti < NN) ? (z + ((size_t)b * NN + ti) * DM)
                                         : (patch + (size_t)b * DM);
            val = ((const float4*)src)[q4];
        }
        *((float4*)&zrow[r][q4 * 4]) = val;
    }
    __syncthreads();

    const float* W    = (mat == 0) ? Wq : (mat == 1) ? Wk : Wv;
    const float* bias = (mat == 0) ? bq : (mat == 1) ? bk : bv;

    float a0x = 0.f, a0y = 0.f, a0z = 0.f, a0w = 0.f;
    float a1x = 0.f, a1y = 0.f, a1z = 0.f, a1w = 0.f;
#pragma unroll 8
    for (int kk = 0; kk < DM; ++kk) {
        float4 w4 = *((const float4*)(W + kk * DM + cg * 4));
        float z0 = zrow[rs][kk];
        float z1 = zrow[rs + 4][kk];
        a0x = fmaf(z0, w4.x, a0x); a0y = fmaf(z0, w4.y, a0y);
        a0z = fmaf(z0, w4.z, a0z); a0w = fmaf(z0, w4.w, a0w);
        a1x = fmaf(z1, w4.x, a1x); a1y = fmaf(z1, w4.y, a1y);
        a1z = fmaf(z1, w4.z, a1z); a1w = fmaf(z1, w4.w, a1w);
    }
    float4 b4 = *((const float4*)(bias + cg * 4));
    float4 o0 = make_float4(a0x + b4.x, a0y + b4.y, a0z + b4.z, a0w + b4.w);
    float4 o1 = make_float4(a1x + b4.x, a1y + b4.y, a1z + b4.z, a1w + b4.w);

#pragma unroll
    for (int rr = 0; rr < 2; ++rr) {
        int row = r0 + rs + rr * 4;
        if (row >= NROWS) break;
        float4 val = rr ? o1 : o0;
        int b = row / NP1, ti = row % NP1;
        if (mat == 0) {
            if (ti < NN) ((float4*)(q + ((size_t)b * NN + ti) * DM))[cg] = val;
        } else if (mat == 1) {
            ((float4*)(k + ((size_t)b * NP1 + ti) * DM))[cg] = val;
        } else {
            ((float4*)(v + ((size_t)b * NP1 + ti) * DM))[cg] = val;
        }
    }
}

// ---------------- wave-autonomous: scan + sparse attention + out-proj ----------------
// ONE WAVE PER QUERY, zero block barriers. 64 lanes = 8 heads x 8 key-slots.
// Each wave: (1) writes the full sbias table itself (duplicate identical-value
// writes across waves are benign; a wave reads only after its own writes, and
// same-wave LDS ops are in-order), (2) scans all 2048 agents (32 independent
// unrolled iters -> deep MLP) appending to its PRIVATE cand list via LDS
// atomics, (3) in-register 16-wide dots over keys s, s+8, ..., (4) slot
// reduction via 3 shfl_xor steps, (5) stages its 128-float row in private
// LDS and does the out-projection with float4 Wo loads (lane-pairs split kk).
// No-max softmax: logits are O(0.3), exp-safe. Dead query: no keys, patch
// keeps l>0, output gated to 0.

__global__ __launch_bounds__(256) void attn_out_kernel(
    const float* __restrict__ q, const float* __restrict__ k, const float* __restrict__ v,
    const int* __restrict__ positions, const float* __restrict__ alive,
    const float* __restrict__ rel_bias, const float* __restrict__ Wo,
    const float* __restrict__ bo, float* __restrict__ out) {
    const int tid = threadIdx.x;
    const int w = tid >> 6;           // wave 0..3
    const int ln = tid & 63;
    const int h = ln >> 3;            // 0..7 head
    const int s = ln & 7;             // 0..7 key slot
    const int bi = blockIdx.x * WPB + w;
    const int b = bi >> 11;
    const int i = bi & (NN - 1);

    __shared__ float sbias[NH * 81];
    __shared__ int   cand[WPB][CAND];
    __shared__ int   mcount[WPB];
    __shared__ float srow[WPB][DM];

    // every wave writes the whole table (reads come after own writes: safe)
    for (int t = ln; t < NH * 81; t += 64) sbias[t] = rel_bias[t];
    if (ln == 0) mcount[w] = 0;

    const int pix = positions[bi * 2 + 0];
    const int piy = positions[bi * 2 + 1];
    const float al = alive[bi];
    const float* kb = k + (size_t)b * NP1 * DM;
    const float* vb = v + (size_t)b * NP1 * DM;

    // q segment for head h, pre-scaled by 1/sqrt(dk)
    const float4* qr = (const float4*)(q + (size_t)bi * DM + h * DK);
    float4 q0 = qr[0], q1 = qr[1], q2 = qr[2], q3 = qr[3];
    q0.x *= 0.25f; q0.y *= 0.25f; q0.z *= 0.25f; q0.w *= 0.25f;
    q1.x *= 0.25f; q1.y *= 0.25f; q1.z *= 0.25f; q1.w *= 0.25f;
    q2.x *= 0.25f; q2.y *= 0.25f; q2.z *= 0.25f; q2.w *= 0.25f;
    q3.x *= 0.25f; q3.y *= 0.25f; q3.z *= 0.25f; q3.w *= 0.25f;

    // scan all agents of this batch (skip entirely for dead query)
    if (al > 0.5f) {
        const int2* pb = (const int2*)(positions + (size_t)b * NN * 2);
        const float* ab = alive + (size_t)b * NN;
#pragma unroll 8
        for (int u = 0; u < NN / 64; ++u) {
            int j = u * 64 + ln;
            int2 pj = pb[j];
            float aj = ab[j];
            int dx = pj.x - pix; dx = dx < 0 ? -dx : dx;
            int dy = pj.y - piy; dy = dy < 0 ? -dy : dy;
            int ch = dx > dy ? dx : dy;
            if (ch <= RWIN && aj > 0.5f && j != i) {
                int slot = atomicAdd(&mcount[w], 1);
                if (slot < CAND) cand[w][slot] = j | (pj.x << 16) | (pj.y << 24);
            }
        }
    }
    __builtin_amdgcn_wave_barrier(); // scheduling fence; HW LDS is in-order per wave
    int M = (al > 0.5f) ? mcount[w] : 0;
    if (M > CAND) M = CAND;

    float l = 0.f;
    float o[16];
#pragma unroll
    for (int d2 = 0; d2 < 16; ++d2) o[d2] = 0.f;

    if (s == 0) { // patch column: always allowed, no bias; keeps l>0 for dead queries
        const float4* kr = (const float4*)(kb + (size_t)NN * DM + h * DK);
        float4 k0 = kr[0], k1 = kr[1], k2 = kr[2], k3 = kr[3];
        float d0 = q0.x * k0.x; d0 = fmaf(q0.y, k0.y, d0); d0 = fmaf(q0.z, k0.z, d0); d0 = fmaf(q0.w, k0.w, d0);
        float d1 = q1.x * k1.x; d1 = fmaf(q1.y, k1.y, d1); d1 = fmaf(q1.z, k1.z, d1); d1 = fmaf(q1.w, k1.w, d1);
        float d2_ = q2.x * k2.x; d2_ = fmaf(q2.y, k2.y, d2_); d2_ = fmaf(q2.z, k2.z, d2_); d2_ = fmaf(q2.w, k2.w, d2_);
        float d3 = q3.x * k3.x; d3 = fmaf(q3.y, k3.y, d3); d3 = fmaf(q3.z, k3.z, d3); d3 = fmaf(q3.w, k3.w, d3);
        float p = __expf((d0 + d1) + (d2_ + d3));
        const float4* vr = (const float4*)(vb + (size_t)NN * DM + h * DK);
        float4 v0 = vr[0], v1 = vr[1], v2 = vr[2], v3 = vr[3];
        l += p;
        o[0] = fmaf(p, v0.x, o[0]);  o[1] = fmaf(p, v0.y, o[1]);
        o[2] = fmaf(p, v0.z, o[2]);  o[3] = fmaf(p, v0.w, o[3]);
        o[4] = fmaf(p, v1.x, o[4]);  o[5] = fmaf(p, v1.y, o[5]);
        o[6] = fmaf(p, v1.z, o[6]);  o[7] = fmaf(p, v1.w, o[7]);
        o[8] = fmaf(p, v2.x, o[8]);  o[9] = fmaf(p, v2.y, o[9]);
        o[10] = fmaf(p, v2.z, o[10]); o[11] = fmaf(p, v2.w, o[11]);
        o[12] = fmaf(p, v3.x, o[12]); o[13] = fmaf(p, v3.y, o[13]);
        o[14] = fmaf(p, v3.z, o[14]); o[15] = fmaf(p, v3.w, o[15]);
    }

    for (int t = s; t < M; t += 8) {
        int packed = cand[w][t];
        int j = packed & 0xFFFF;
        const float4* kr = (const float4*)(kb + (size_t)j * DM + h * DK);
        float4 k0 = kr[0], k1 = kr[1], k2 = kr[2], k3 = kr[3];
        const float4* vr = (const float4*)(vb + (size_t)j * DM + h * DK);
        float4 v0 = vr[0], v1 = vr[1], v2 = vr[2], v3 = vr[3];
        float d0 = q0.x * k0.x; d0 = fmaf(q0.y, k0.y, d0); d0 = fmaf(q0.z, k0.z, d0); d0 = fmaf(q0.w, k0.w, d0);
        float d1 = q1.x * k1.x; d1 = fmaf(q1.y, k1.y, d1); d1 = fmaf(q1.z, k1.z, d1); d1 = fmaf(q1.w, k1.w, d1);
        float d2_ = q2.x * k2.x; d2_ = fmaf(q2.y, k2.y, d2_); d2_ = fmaf(q2.z, k2.z, d2_); d2_ = fmaf(q2.w, k2.w, d2_);
        float d3 = q3.x * k3.x; d3 = fmaf(q3.y, k3.y, d3); d3 = fmaf(q3.z, k3.z, d3); d3 = fmaf(q3.w, k3.w, d3);
        int pjx = (packed >> 16) & 0xFF;
        int pjy = (packed >> 24) & 0xFF;
        float bias = sbias[h * 81 + (pjx - pix + RWIN) * 9 + (pjy - piy + RWIN)];
        float p = __expf((d0 + d1) + (d2_ + d3) + bias);
        l += p;
        o[0] = fmaf(p, v0.x, o[0]);  o[1] = fmaf(p, v0.y, o[1]);
        o[2] = fmaf(p, v0.z, o[2]);  o[3] = fmaf(p, v0.w, o[3]);
        o[4] = fmaf(p, v1.x, o[4]);  o[5] = fmaf(p, v1.y, o[5]);
        o[6] = fmaf(p, v1.z, o[6]);  o[7] = fmaf(p, v1.w, o[7]);
        o[8] = fmaf(p, v2.x, o[8]);  o[9] = fmaf(p, v2.y, o[9]);
        o[10] = fmaf(p, v2.z, o[10]); o[11] = fmaf(p, v2.w, o[11]);
        o[12] = fmaf(p, v3.x, o[12]); o[13] = fmaf(p, v3.y, o[13]);
        o[14] = fmaf(p, v3.z, o[14]); o[15] = fmaf(p, v3.w, o[15]);
    }

    // reduce over the 8 key-slots: butterfly within each 8-lane s-group
#pragma unroll
    for (int d = 1; d < 8; d <<= 1) {
        l += __shfl_xor(l, d, 64);
#pragma unroll
        for (int e = 0; e < 16; ++e) o[e] += __shfl_xor(o[e], d, 64);
    }
    float rl = 1.f / l;
    if (s < 4) { // lanes s=0..3 write dims s*4..s*4+3 of head h
#pragma unroll
        for (int e = 0; e < 4; ++e) srow[w][h * DK + s * 4 + e] = o[s * 4 + e] * rl;
    }
    __builtin_amdgcn_wave_barrier();

    // out-projection: lane pair (2m, 2m+1) computes cols m*4..m*4+3;
    // each lane does half the kk range, combined via shfl_xor(1).
    {
        const int m = ln >> 1;
        const int half = ln & 1;
        const float* Wb = Wo + (size_t)half * 64 * DM + m * 4;
        const float* sr = &srow[w][half * 64];
        float ax = 0.f, ay = 0.f, az = 0.f, aw = 0.f;
#pragma unroll 16
        for (int kk = 0; kk < 64; ++kk) {
            float sv = sr[kk];
            float4 w4 = *((const float4*)(Wb + (size_t)kk * DM));
            ax = fmaf(sv, w4.x, ax); ay = fmaf(sv, w4.y, ay);
            az = fmaf(sv, w4.z, az); aw = fmaf(sv, w4.w, aw);
        }
        ax += __shfl_xor(ax, 1, 64); ay += __shfl_xor(ay, 1, 64);
        az += __shfl_xor(az, 1, 64); aw += __shfl_xor(aw, 1, 64);
        if (half == 0) {
            float ga = al > 0.5f ? 1.f : 0.f;
            float4 b4 = *((const float4*)(bo + m * 4));
            float4 r;
            r.x = (ax + b4.x) * ga; r.y = (ay + b4.y) * ga;
            r.z = (az + b4.z) * ga; r.w = (aw + b4.w) * ga;
            ((float4*)(out + (size_t)bi * DM))[m] = r;
        }
    }
}

extern "C" void kernel_launch(void* const* d_in, const int* in_sizes, int n_in,
                              void* d_out, int out_size, void* d_ws, size_t ws_size,
                              hipStream_t stream) {
    const float* z         = (const float*)d_in[0];
    const float* patch     = (const float*)d_in[1];
    const int*   positions = (const int*)d_in[2];
    const float* alive     = (const float*)d_in[3];
    const float* Wq        = (const float*)d_in[4];
    const float* bq        = (const float*)d_in[5];
    const float* Wk        = (const float*)d_in[6];
    const float* bk        = (const float*)d_in[7];
    const float* Wv        = (const float*)d_in[8];
    const float* bv        = (const float*)d_in[9];
    const float* Wo        = (const float*)d_in[10];
    const float* bo        = (const float*)d_in[11];
    const float* rel_bias  = (const float*)d_in[12];
    float* out = (float*)d_out;

    char* ws = (char*)d_ws;
    size_t off = 0;
    auto alloc = [&](size_t bytes) -> void* {
        void* p = ws + off;
        off += (bytes + 255) & ~(size_t)255;
        return p;
    };
    float* q = (float*)alloc((size_t)BB * NN * DM * 4);
    float* k = (float*)alloc((size_t)BB * NP1 * DM * 4);
    float* v = (float*)alloc((size_t)BB * NP1 * DM * 4);

    qkv_kernel<<<(BB * NP1 + QKV_ROWS - 1) / QKV_ROWS, 384, 0, stream>>>(z, patch, Wq, bq, Wk, bk, Wv, bv, q, k, v);
    attn_out_kernel<<<(BB * NN) / WPB, 256, 0, stream>>>(q, k, v, positions, alive, rel_bias, Wo, bo, out);
}

// Round 10
// 126.043 us; speedup vs baseline: 1.1450x; 1.1450x over previous
//
#include <hip/hip_runtime.h>
#include <hip/hip_fp16.h>
#include <math.h>

#define BB 2
#define NN 2048
#define NP1 2049
#define DM 128
#define NH 8
#define DK 16
#define RWIN 4
#define GRID_W 64
#define QPB 8        /* queries per attn block */
#define CAND_PQ 160  /* per-query candidate cap; binom mean ~36, sd ~6 -> 20 sigma */

__device__ __forceinline__ void unpack8(uint4 r, float* f) {
    float2 t;
    t = __half22float2(*(const __half2*)&r.x); f[0] = t.x; f[1] = t.y;
    t = __half22float2(*(const __half2*)&r.y); f[2] = t.x; f[3] = t.y;
    t = __half22float2(*(const __half2*)&r.z); f[4] = t.x; f[5] = t.y;
    t = __half22float2(*(const __half2*)&r.w); f[6] = t.x; f[7] = t.y;
}

// ---------------- QKV projection ----------------
// 384 threads = 3 mats x (32 col-groups x 4 row-slots). Thread owns 4
// consecutive output columns (float4 W loads) and rows rs, rs+4.
// K and V are stored as fp16 (halves the gathered working set for attn);
// Q stays fp32 (read coalesced once, and keeps logit error budget low).

#define QKV_ROWS 8

__global__ __launch_bounds__(384) void qkv_kernel(
    const float* __restrict__ z, const float* __restrict__ patch,
    const float* __restrict__ Wq, const float* __restrict__ bq,
    const float* __restrict__ Wk, const float* __restrict__ bk,
    const float* __restrict__ Wv, const float* __restrict__ bv,
    float* __restrict__ q, __half* __restrict__ k, __half* __restrict__ v) {
    __shared__ float zrow[QKV_ROWS][DM];
    const int tid = threadIdx.x;
    const int mat = tid >> 7;          // 0=q 1=k 2=v, wave-uniform
    const int rem = tid & 127;
    const int cg = rem & 31;           // col-group: cols cg*4..cg*4+3
    const int rs = rem >> 5;           // row-slot: rows rs, rs+4
    const int r0 = blockIdx.x * QKV_ROWS;
    const int NROWS = BB * NP1;

    if (tid < QKV_ROWS * DM / 4) {
        int r = tid >> 5, q4 = tid & 31;
        int row = r0 + r;
        float4 val = make_float4(0.f, 0.f, 0.f, 0.f);
        if (row < NROWS) {
            int b = row / NP1, ti = row % NP1;
            const float* src = (ti < NN) ? (z + ((size_t)b * NN + ti) * DM)
                                         : (patch + (size_t)b * DM);
            val = ((const float4*)src)[q4];
        }
        *((float4*)&zrow[r][q4 * 4]) = val;
    }
    __syncthreads();

    const float* W    = (mat == 0) ? Wq : (mat == 1) ? Wk : Wv;
    const float* bias = (mat == 0) ? bq : (mat == 1) ? bk : bv;

    float a0x = 0.f, a0y = 0.f, a0z = 0.f, a0w = 0.f;
    float a1x = 0.f, a1y = 0.f, a1z = 0.f, a1w = 0.f;
#pragma unroll 8
    for (int kk = 0; kk < DM; ++kk) {
        float4 w4 = *((const float4*)(W + kk * DM + cg * 4));
        float z0 = zrow[rs][kk];
        float z1 = zrow[rs + 4][kk];
        a0x = fmaf(z0, w4.x, a0x); a0y = fmaf(z0, w4.y, a0y);
        a0z = fmaf(z0, w4.z, a0z); a0w = fmaf(z0, w4.w, a0w);
        a1x = fmaf(z1, w4.x, a1x); a1y = fmaf(z1, w4.y, a1y);
        a1z = fmaf(z1, w4.z, a1z); a1w = fmaf(z1, w4.w, a1w);
    }
    float4 b4 = *((const float4*)(bias + cg * 4));
    float4 o0 = make_float4(a0x + b4.x, a0y + b4.y, a0z + b4.z, a0w + b4.w);
    float4 o1 = make_float4(a1x + b4.x, a1y + b4.y, a1z + b4.z, a1w + b4.w);

#pragma unroll
    for (int rr = 0; rr < 2; ++rr) {
        int row = r0 + rs + rr * 4;
        if (row >= NROWS) break;
        float4 val = rr ? o1 : o0;
        int b = row / NP1, ti = row % NP1;
        if (mat == 0) {
            if (ti < NN) ((float4*)(q + ((size_t)b * NN + ti) * DM))[cg] = val;
        } else {
            __half2 p0 = __floats2half2_rn(val.x, val.y);
            __half2 p1 = __floats2half2_rn(val.z, val.w);
            uint2 st;
            st.x = *(unsigned int*)&p0;
            st.y = *(unsigned int*)&p1;
            __half* dst = ((mat == 1) ? k : v) + ((size_t)b * NP1 + ti) * DM;
            ((uint2*)dst)[cg] = st;
        }
    }
}

// ---------------- fused: 8-query neighbor scan + sparse attention + out-proj ----------------
// R7 structure. K/V gathers are fp16: one uint4 = full 16-elem head segment
// (4x fewer gather VMEM instructions, half the fetched bytes).

__global__ __launch_bounds__(256) void attn_out_kernel(
    const float* __restrict__ q, const __half* __restrict__ k, const __half* __restrict__ v,
    const int* __restrict__ positions, const float* __restrict__ alive,
    const float* __restrict__ rel_bias, const float* __restrict__ Wo,
    const float* __restrict__ bo, float* __restrict__ out) {
    const int tid = threadIdx.x;
    const int qq = tid >> 5;          // 0..7 query in group
    const int lane = tid & 31;
    const int h = lane >> 2;          // 0..7 head
    const int s = lane & 3;           // 0..3 key slot
    const int r0 = blockIdx.x * QPB;  // global query base (same batch: NN%QPB==0)
    const int b = r0 >> 11;
    const int bi = r0 + qq;

    __shared__ float sbias[NH * 81];
    __shared__ int   spx[QPB], spy[QPB];
    __shared__ float sal[QPB];
    __shared__ int   mcount[QPB];
    __shared__ int   cand[QPB][CAND_PQ];
    __shared__ float po[QPB * 4][DM + 1];
    __shared__ float pl[QPB * 4][NH + 1];
    __shared__ float srow[QPB][DM + 1];

    if (tid < QPB) {
        mcount[tid] = 0;
        int gbi = r0 + tid;
        spx[tid] = positions[gbi * 2 + 0];
        spy[tid] = positions[gbi * 2 + 1];
        sal[tid] = alive[gbi];
    }
    for (int t = tid; t < NH * 81; t += 256) sbias[t] = rel_bias[t];

    const __half* kb = k + (size_t)b * NP1 * DM;
    const __half* vb = v + (size_t)b * NP1 * DM;

    // q segment for (query qq, head h), pre-scaled by 1/sqrt(dk)
    float qf[16];
    {
        const float4* qr = (const float4*)(q + (size_t)bi * DM + h * DK);
#pragma unroll
        for (int e = 0; e < 4; ++e) {
            float4 t4 = qr[e];
            qf[e * 4 + 0] = t4.x * 0.25f; qf[e * 4 + 1] = t4.y * 0.25f;
            qf[e * 4 + 2] = t4.z * 0.25f; qf[e * 4 + 3] = t4.w * 0.25f;
        }
    }

    __syncthreads(); // spos/sal/mcount/sbias visible

    int qx[QPB], qy[QPB], qi[QPB];
    float qa[QPB];
#pragma unroll
    for (int u = 0; u < QPB; ++u) {
        qx[u] = spx[u]; qy[u] = spy[u]; qa[u] = sal[u];
        qi[u] = (r0 + u) & (NN - 1);
    }

    // one scan over all agents, 8 query tests each
    const int2* pb = (const int2*)(positions + (size_t)b * NN * 2);
    const float* ab = alive + (size_t)b * NN;
#pragma unroll
    for (int u = 0; u < NN / 256; ++u) {
        int j = u * 256 + tid;
        int2 pj = pb[j];
        float aj = ab[j];
        if (aj > 0.5f) {
            int packed = j | (pj.x << 16) | (pj.y << 24);
#pragma unroll
            for (int qn = 0; qn < QPB; ++qn) {
                int dx = pj.x - qx[qn]; dx = dx < 0 ? -dx : dx;
                int dy = pj.y - qy[qn]; dy = dy < 0 ? -dy : dy;
                int ch = dx > dy ? dx : dy;
                if (ch <= RWIN && j != qi[qn] && qa[qn] > 0.5f) {
                    int slot = atomicAdd(&mcount[qn], 1);
                    if (slot < CAND_PQ) cand[qn][slot] = packed;
                }
            }
        }
    }
    __syncthreads();
    int M = mcount[qq]; if (M > CAND_PQ) M = CAND_PQ;
    const int pix = qx[qq], piy = qy[qq];

    float l = 0.f;
    float o[16];
#pragma unroll
    for (int e = 0; e < 16; ++e) o[e] = 0.f;

    if (s == 0) { // patch column: always allowed, no bias; keeps l>0 for dead queries
        const uint4* kr = (const uint4*)(kb + (size_t)NN * DM + h * DK);
        uint4 ka = kr[0], kb4 = kr[1];
        const uint4* vr = (const uint4*)(vb + (size_t)NN * DM + h * DK);
        uint4 va = vr[0], vb4 = vr[1];
        float kf[16], vf[16];
        unpack8(ka, kf); unpack8(kb4, kf + 8);
        unpack8(va, vf); unpack8(vb4, vf + 8);
        float d = 0.f;
#pragma unroll
        for (int e = 0; e < 16; ++e) d = fmaf(qf[e], kf[e], d);
        float p = __expf(d);
        l += p;
#pragma unroll
        for (int e = 0; e < 16; ++e) o[e] = fmaf(p, vf[e], o[e]);
    }

    for (int t = s; t < M; t += 4) {
        int packed = cand[qq][t];
        int j = packed & 0xFFFF;
        const uint4* kr = (const uint4*)(kb + (size_t)j * DM + h * DK);
        uint4 ka = kr[0], kb4 = kr[1];
        const uint4* vr = (const uint4*)(vb + (size_t)j * DM + h * DK);
        uint4 va = vr[0], vb4 = vr[1];
        float kf[16], vf[16];
        unpack8(ka, kf); unpack8(kb4, kf + 8);
        unpack8(va, vf); unpack8(vb4, vf + 8);
        float d = 0.f;
#pragma unroll
        for (int e = 0; e < 16; ++e) d = fmaf(qf[e], kf[e], d);
        int pjx = (packed >> 16) & 0xFF;
        int pjy = (packed >> 24) & 0xFF;
        float bias = sbias[h * 81 + (pjx - pix + RWIN) * 9 + (pjy - piy + RWIN)];
        float p = __expf(d + bias);
        l += p;
#pragma unroll
        for (int e = 0; e < 16; ++e) o[e] = fmaf(p, vf[e], o[e]);
    }

    // reduction over the 4 key-slots via LDS
    {
        const int prow = qq * 4 + s;
#pragma unroll
        for (int e = 0; e < 16; ++e) po[prow][h * DK + e] = o[e];
        pl[prow][h] = l;
    }
    __syncthreads();
    {
        const int c = tid & 127;
        const int g = tid >> 7; // 0/1 -> queries g*4..g*4+3
        const int ch = c >> 4;
#pragma unroll
        for (int qn = 0; qn < 4; ++qn) {
            int qq2 = g * 4 + qn;
            float acc = 0.f, lh = 0.f;
#pragma unroll
            for (int ss = 0; ss < 4; ++ss) {
                acc += po[qq2 * 4 + ss][c];
                lh  += pl[qq2 * 4 + ss][ch];
            }
            srow[qq2][c] = acc / lh;
        }
    }
    __syncthreads();

    // output projection: thread (oq = tid>>5, c = lane) -> cols c*4..c*4+3
    {
        const int oq = tid >> 5;
        const int c4 = lane;
        float ax = 0.f, ay = 0.f, az = 0.f, aw = 0.f;
#pragma unroll 8
        for (int kk = 0; kk < DM; ++kk) {
            float sv = srow[oq][kk];
            float4 w4 = *((const float4*)(Wo + kk * DM + c4 * 4));
            ax = fmaf(sv, w4.x, ax); ay = fmaf(sv, w4.y, ay);
            az = fmaf(sv, w4.z, az); aw = fmaf(sv, w4.w, aw);
        }
        float ga = sal[oq] > 0.5f ? 1.f : 0.f;
        float4 b4 = *((const float4*)(bo + c4 * 4));
        float4 r;
        r.x = (ax + b4.x) * ga; r.y = (ay + b4.y) * ga;
        r.z = (az + b4.z) * ga; r.w = (aw + b4.w) * ga;
        ((float4*)(out + (size_t)(r0 + oq) * DM))[c4] = r;
    }
}

extern "C" void kernel_launch(void* const* d_in, const int* in_sizes, int n_in,
                              void* d_out, int out_size, void* d_ws, size_t ws_size,
                              hipStream_t stream) {
    const float* z         = (const float*)d_in[0];
    const float* patch     = (const float*)d_in[1];
    const int*   positions = (const int*)d_in[2];
    const float* alive     = (const float*)d_in[3];
    const float* Wq        = (const float*)d_in[4];
    const float* bq        = (const float*)d_in[5];
    const float* Wk        = (const float*)d_in[6];
    const float* bk        = (const float*)d_in[7];
    const float* Wv        = (const float*)d_in[8];
    const float* bv        = (const float*)d_in[9];
    const float* Wo        = (const float*)d_in[10];
    const float* bo        = (const float*)d_in[11];
    const float* rel_bias  = (const float*)d_in[12];
    float* out = (float*)d_out;

    char* ws = (char*)d_ws;
    size_t off = 0;
    auto alloc = [&](size_t bytes) -> void* {
        void* p = ws + off;
        off += (bytes + 255) & ~(size_t)255;
        return p;
    };
    float*  q = (float*)alloc((size_t)BB * NN * DM * 4);
    __half* k = (__half*)alloc((size_t)BB * NP1 * DM * 2);
    __half* v = (__half*)alloc((size_t)BB * NP1 * DM * 2);

    qkv_kernel<<<(BB * NP1 + QKV_ROWS - 1) / QKV_ROWS, 384, 0, stream>>>(z, patch, Wq, bq, Wk, bk, Wv, bv, q, k, v);
    attn_out_kernel<<<(BB * NN) / QPB, 256, 0, stream>>>(q, k, v, positions, alive, rel_bias, Wo, bo, out);
}